// Round 9
// baseline (526.152 us; speedup 1.0000x reference)
//
#include <hip/hip_runtime.h>
#include <hip/hip_bf16.h>

// BasicGCN: out = log_softmax( A @ (relu(A @ x @ W1 + b1) @ W2) + b2 )
// R17: two changes on the R16 base (521.1us):
//  1. agg1 column-split: xq stored as two half-tables xqA/xqB (12.8MB each,
//     cols 0-127 / 128-255); k_agg1h runs twice, 8 lanes/node x 16B/lane
//     (same request width as R16 -- NOT R7's narrow-request slicing).
//     Halves the gather working set per pass to raise per-XCD L2 hit.
//     Scale remains per FULL row (computed before split) -> numerics identical.
//  2. quant2 fused into gemm2 epilogue (acc -> LDS f32[64][65] -> row max ->
//     tq/w2v). Kills the tb bf16 round-trip (25.6MB) and one launch.

typedef __bf16 bf16;
typedef bf16 bf16x8 __attribute__((ext_vector_type(8)));
typedef float f32x4 __attribute__((ext_vector_type(4)));
typedef float f32x2 __attribute__((ext_vector_type(2)));

#define NBLK 256  // edge-chunk blocks for bucketing passes

// ---------------- pass 1: per-block bucket histogram (LDS) ----------------
__global__ __launch_bounds__(256) void k_b1(const int* __restrict__ edge, int E, int chunk,
                                            int NB, int* __restrict__ gcnt) {
    __shared__ int cnt[512];
    int tid = threadIdx.x;
    for (int i = tid; i < NB; i += 256) cnt[i] = 0;
    __syncthreads();
    int s = blockIdx.x * chunk, e = min(s + chunk, E);
    for (int i = s + tid; i < e; i += 256) atomicAdd(&cnt[edge[E + i] >> 9], 1);
    __syncthreads();
    for (int i = tid; i < NB; i += 256) gcnt[blockIdx.x * NB + i] = cnt[i];
}

// ---------------- pass 2a: bucket starts ----------------
__global__ void k_b2(const int* __restrict__ gcnt, int NB, int E, int* __restrict__ bstart) {
    __shared__ int col[256];
    int k = threadIdx.x;
    int sum = 0;
    if (k < NB)
        for (int b = 0; b < NBLK; ++b) sum += gcnt[b * NB + k];
    col[k] = sum;
    __syncthreads();
    for (int o = 1; o < 256; o <<= 1) {
        int v = (k >= o) ? col[k - o] : 0;
        __syncthreads();
        col[k] += v;
        __syncthreads();
    }
    if (k < NB) bstart[k] = col[k] - sum;
    if (k == 0) bstart[NB] = E;
}

// ---------------- pass 2b: per-(block,bucket) bases ----------------
__global__ void k_b2b(int* __restrict__ gcnt, int NB, const int* __restrict__ bstart) {
    __shared__ int col[256];
    int b = threadIdx.x;  // NBLK == 256
    int k = blockIdx.x;
    int v = gcnt[b * NB + k];
    col[b] = v;
    __syncthreads();
    for (int o = 1; o < 256; o <<= 1) {
        int t = (b >= o) ? col[b - o] : 0;
        __syncthreads();
        col[b] += t;
        __syncthreads();
    }
    gcnt[b * NB + k] = bstart[k] + col[b] - v;
}

// ---------------- pass 3: scatter edges into bucket-grouped ebuf ----------------
// packed: src (17 bits) | (dst & 511) << 17
__global__ __launch_bounds__(256) void k_b3(const int* __restrict__ edge, int E, int chunk,
                                            int NB, const int* __restrict__ base,
                                            int* __restrict__ ebuf) {
    __shared__ int cnt[512];
    __shared__ int bs[512];
    int tid = threadIdx.x;
    for (int i = tid; i < NB; i += 256) {
        cnt[i] = 0;
        bs[i] = base[blockIdx.x * NB + i];
    }
    __syncthreads();
    int s = blockIdx.x * chunk, e = min(s + chunk, E);
    for (int i = s + tid; i < e; i += 256) {
        int sv = edge[i], dv = edge[E + i];
        int k = dv >> 9;
        int r = atomicAdd(&cnt[k], 1);  // LDS atomic
        ebuf[bs[k] + r] = sv | ((dv & 511) << 17);
    }
}

// ---------------- pass 4+5 merged: per-bucket hist + local scan -> off, dinv, ws ----------------
// off[node] = bstart[bucket] + exclusive_scan_within_bucket(deg); ws = dinv*scale
__global__ __launch_bounds__(256) void k_b45(const int* __restrict__ ebuf,
                                             const int* __restrict__ bstart,
                                             const float* __restrict__ scale, int n, int E,
                                             int NB, int* __restrict__ off,
                                             float* __restrict__ dinv,
                                             float* __restrict__ ws) {
    __shared__ int cnt[512];
    __shared__ int red[256];
    int tid = threadIdx.x;
    int k = blockIdx.x;
    cnt[tid] = 0;
    cnt[tid + 256] = 0;
    __syncthreads();
    int s = bstart[k], e = bstart[k + 1];
    for (int i = s + tid; i < e; i += 256) atomicAdd(&cnt[(ebuf[i] >> 17) & 511], 1);
    __syncthreads();
    int c0 = cnt[tid * 2], c1 = cnt[tid * 2 + 1];
    int sum = c0 + c1;
    red[tid] = sum;
    __syncthreads();
    for (int o = 1; o < 256; o <<= 1) {
        int v = (tid >= o) ? red[tid - o] : 0;
        __syncthreads();
        red[tid] += v;
        __syncthreads();
    }
    int ex = red[tid] - sum;  // exclusive prefix over pairs
    int base = k << 9;
    int g0 = base + tid * 2, g1 = g0 + 1;
    int o0 = s + ex, o1 = s + ex + c0;
    if (g0 < n) {
        off[g0] = o0;
        float d0 = rsqrtf((float)(c0 + 1));
        dinv[g0] = d0;
        ws[g0] = d0 * scale[g0];
    } else if (g0 == n) off[g0] = o0;
    if (g1 < n) {
        off[g1] = o1;
        float d1 = rsqrtf((float)(c1 + 1));
        dinv[g1] = d1;
        ws[g1] = d1 * scale[g1];
    } else if (g1 == n) off[g1] = o1;
    if (k == NB - 1 && tid == 0) off[n] = E;
}

// ---------------- pass 6: per-bucket CSR fill (LDS ranks, LDS off) ----------------
// pair.x = sv<<8; pair.y = ws[sv] = dinv[sv]*scale[sv]
__global__ __launch_bounds__(256) void k_b6(const int* __restrict__ ebuf,
                                            const int* __restrict__ bstart,
                                            const int* __restrict__ off,
                                            const float* __restrict__ ws, int n,
                                            int2* __restrict__ pair) {
    __shared__ int cnt[512];
    __shared__ int offl[512];
    int tid = threadIdx.x;
    int k = blockIdx.x;
    int base = k << 9;
    cnt[tid] = 0;
    cnt[tid + 256] = 0;
    offl[tid] = (base + tid < n) ? off[base + tid] : 0;
    offl[tid + 256] = (base + 256 + tid < n) ? off[base + 256 + tid] : 0;
    __syncthreads();
    int s = bstart[k], e = bstart[k + 1];
    for (int i = s + tid; i < e; i += 256) {
        int pk = ebuf[i];
        int sv = pk & 0x1ffff;
        int node = (pk >> 17) & 511;
        int r = atomicAdd(&cnt[node], 1);  // LDS atomic
        pair[offl[node] + r] = make_int2(sv << 8, __float_as_int(ws[sv]));
    }
}

// ---------------- x -> per-row-scaled biased-u8, SPLIT into two half-tables ----------------
// scale is the FULL-row absmax (identical numerics to unsplit); lane<32 -> xqA cols 0-127,
// lane>=32 -> xqB cols 128-255.
__global__ __launch_bounds__(256) void k_quant(const float* __restrict__ x,
                                               unsigned char* __restrict__ xqA,
                                               unsigned char* __restrict__ xqB,
                                               float* __restrict__ scale, int n) {
    int row = blockIdx.x * 4 + (threadIdx.x >> 6);
    int lane = threadIdx.x & 63;
    if (row >= n) return;
    f32x4 v = ((const f32x4*)x)[(size_t)row * 64 + lane];
    float m = fmaxf(fmaxf(fabsf(v[0]), fabsf(v[1])), fmaxf(fabsf(v[2]), fabsf(v[3])));
    for (int o = 32; o > 0; o >>= 1) m = fmaxf(m, __shfl_xor(m, o));
    m = fmaxf(m, 1e-20f);
    float inv = 127.0f / m;
    int b0 = (__float2int_rn(v[0] * inv) + 128) & 255;
    int b1 = (__float2int_rn(v[1] * inv) + 128) & 255;
    int b2 = (__float2int_rn(v[2] * inv) + 128) & 255;
    int b3 = (__float2int_rn(v[3] * inv) + 128) & 255;
    int word = b0 | (b1 << 8) | (b2 << 16) | (b3 << 24);
    if (lane < 32) ((int*)xqA)[(size_t)row * 32 + lane] = word;
    else           ((int*)xqB)[(size_t)row * 32 + (lane - 32)] = word;
    if (lane == 0) scale[row] = m / 127.0f;
}

// ---------------- W1 (256x256) and W2 (256x64) -> transposed bf16, one launch ------
__global__ void k_wt(const float* __restrict__ W1, const float* __restrict__ W2,
                     bf16* __restrict__ W1t, bf16* __restrict__ W2t) {
    int b = blockIdx.x;
    int k = threadIdx.x;
    if (b < 256) W1t[b * 256 + k] = (bf16)W1[k * 256 + b];
    else { int nc = b - 256; W2t[nc * 256 + k] = (bf16)W2[k * 64 + nc]; }
}

// accumulate 16 biased-u8 elements into 8 f32x2; wsum += w
// (float)((u>>8)&255) etc. lower to single v_cvt_f32_ubyte{0..3}
__device__ __forceinline__ void acc16(f32x2 a[8], uint4 t, float w, float& wsum) {
    wsum += w;
    f32x2 w2 = {w, w};
    unsigned u0 = t.x, u1 = t.y, u2 = t.z, u3 = t.w;
    f32x2 c;
    c[0] = (float)(u0 & 255u);         c[1] = (float)((u0 >> 8) & 255u);  a[0] += w2 * c;
    c[0] = (float)((u0 >> 16) & 255u); c[1] = (float)(u0 >> 24);         a[1] += w2 * c;
    c[0] = (float)(u1 & 255u);         c[1] = (float)((u1 >> 8) & 255u);  a[2] += w2 * c;
    c[0] = (float)((u1 >> 16) & 255u); c[1] = (float)(u1 >> 24);         a[3] += w2 * c;
    c[0] = (float)(u2 & 255u);         c[1] = (float)((u2 >> 8) & 255u);  a[4] += w2 * c;
    c[0] = (float)((u2 >> 16) & 255u); c[1] = (float)(u2 >> 24);         a[5] += w2 * c;
    c[0] = (float)(u3 & 255u);         c[1] = (float)((u3 >> 8) & 255u);  a[6] += w2 * c;
    c[0] = (float)((u3 >> 16) & 255u); c[1] = (float)(u3 >> 24);         a[7] += w2 * c;
}

// accumulate 8 biased-u8 elements into 4 f32x2
__device__ __forceinline__ void acc8(f32x2 a[4], int2 t, float w, float& wsum) {
    wsum += w;
    f32x2 w2 = {w, w};
    unsigned u0 = (unsigned)t.x, u1 = (unsigned)t.y;
    f32x2 c;
    c[0] = (float)(u0 & 255u);         c[1] = (float)((u0 >> 8) & 255u);  a[0] += w2 * c;
    c[0] = (float)((u0 >> 16) & 255u); c[1] = (float)(u0 >> 24);         a[1] += w2 * c;
    c[0] = (float)(u1 & 255u);         c[1] = (float)((u1 >> 8) & 255u);  a[2] += w2 * c;
    c[0] = (float)((u1 >> 16) & 255u); c[1] = (float)(u1 >> 24);         a[3] += w2 * c;
}

// ---------------- agg1 half-pass: ax[:, h*128:+128] = A @ xqh ----------------
// 8 nodes/wave, 8 lanes/node, 16B/lane (same request width as R16); 8-deep rotation.
// Gather offset = (sv<<8)>>1 = sv*128 (half-table row stride).
__global__ __launch_bounds__(256) void k_agg1h(const unsigned char* __restrict__ xqh,
                                               const float* __restrict__ wsv,
                                               const int* __restrict__ off,
                                               const int2* __restrict__ pair,
                                               const float* __restrict__ dinv,
                                               bf16* __restrict__ ax, int hofs, int n) {
    int wv = blockIdx.x * 4 + (threadIdx.x >> 6);
    int lane = threadIdx.x & 63;
    int node = wv * 8 + (lane >> 3);
    int l8 = lane & 7;
    if (node >= n) return;
    int s0 = off[node], s1 = off[node + 1];
    float dv = dinv[node];
    const unsigned char* xqb = xqh + l8 * 16;  // per-lane base; gather = xqb + (p.x>>1)
    f32x2 a[8] = {};
    float wsum = 0.0f;
    uint4 xs = *(const uint4*)(xqb + (size_t)node * 128);
    acc16(a, xs, wsv[node], wsum);  // self loop, weight dinv*scale[node]
    int e = s0;
    if (s1 - s0 >= 8) {
        int2 p[8];
#pragma unroll
        for (int q = 0; q < 8; ++q) p[q] = pair[s0 + q];
        e = s0 + 8;
        for (; e + 8 <= s1; e += 8) {
            uint4 t[8];
#pragma unroll
            for (int q = 0; q < 8; ++q)
                t[q] = *(const uint4*)(xqb + ((unsigned)p[q].x >> 1));
            int2 pn[8];
#pragma unroll
            for (int q = 0; q < 8; ++q) pn[q] = pair[e + q];
#pragma unroll
            for (int q = 0; q < 8; ++q) acc16(a, t[q], __int_as_float(p[q].y), wsum);
#pragma unroll
            for (int q = 0; q < 8; ++q) p[q] = pn[q];
        }
        // drain the prefetched 8
        uint4 t[8];
#pragma unroll
        for (int q = 0; q < 8; ++q)
            t[q] = *(const uint4*)(xqb + ((unsigned)p[q].x >> 1));
#pragma unroll
        for (int q = 0; q < 8; ++q) acc16(a, t[q], __int_as_float(p[q].y), wsum);
    }
    for (; e < s1; ++e) {
        int2 p = pair[e];
        uint4 t = *(const uint4*)(xqb + ((unsigned)p.x >> 1));
        acc16(a, t, __int_as_float(p.y), wsum);
    }
    float c = 128.0f * wsum;  // undo the +128 bias
    bf16x8 o0, o1;
#pragma unroll
    for (int j = 0; j < 4; ++j) {
        o0[2 * j]     = (bf16)((a[j][0] - c) * dv);
        o0[2 * j + 1] = (bf16)((a[j][1] - c) * dv);
        o1[2 * j]     = (bf16)((a[4 + j][0] - c) * dv);
        o1[2 * j + 1] = (bf16)((a[4 + j][1] - c) * dv);
    }
    ((bf16x8*)ax)[(size_t)node * 32 + hofs + l8 * 2] = o0;
    ((bf16x8*)ax)[(size_t)node * 32 + hofs + l8 * 2 + 1] = o1;
}

// LDS slot swizzle (slot in 16B units): spreads lane-stride-16B reads across banks.
__device__ __forceinline__ int swz(int s) { return s ^ ((s >> 3) & 7); }

// ---------------- row-panel GEMM (layer 1): C[n x 256] = A[n x 256] @ Bt^T, +bias+relu ----
// 128-row panel, 8 waves (2M x 4N), acc[4][4]/wave, 8 ds_read : 16 MFMA per k-step.
__global__ __launch_bounds__(512) void k_gemmp(const bf16* __restrict__ A,
                                               const bf16* __restrict__ Bt,
                                               const float* __restrict__ bias,
                                               bf16* __restrict__ C, int n) {
    __shared__ __align__(16) bf16 As[8 * 64 * 8];    // 128 rows x 32 k (8KB)
    __shared__ __align__(16) bf16 Bs[16 * 64 * 8];   // 256 N x 32 k (16KB)
    int tid = threadIdx.x;           // 0..511
    int bm = blockIdx.x * 128;
    int w = tid >> 6, lane = tid & 63;
    int wm = w >> 2;                 // 0..1: row half (64 rows)
    int wn = w & 3;                  // 0..3: col quarter (64 cols)

    int r = tid >> 2;                // 0..127
    int cq = tid & 3;
    int a_slot = swz(((r >> 4) * 64) + cq * 16 + (r & 15));
    int arow = bm + r; if (arow > n - 1) arow = n - 1;

    f32x4 acc[4][4] = {};

    for (int k0 = 0; k0 < 256; k0 += 32) {
        __syncthreads();
        uint4 av = *(const uint4*)(A + (size_t)arow * 256 + k0 + cq * 8);
        *(uint4*)(As + a_slot * 8) = av;
#pragma unroll
        for (int rep = 0; rep < 2; ++rep) {
            int r2 = rep * 128 + r;
            uint4 bv = *(const uint4*)(Bt + (size_t)r2 * 256 + k0 + cq * 8);
            *(uint4*)(Bs + swz(((r2 >> 4) * 64) + cq * 16 + (r2 & 15)) * 8) = bv;
        }
        __syncthreads();
        bf16x8 af[4], bfr[4];
#pragma unroll
        for (int i = 0; i < 4; ++i)
            af[i] = *(const bf16x8*)(As + swz(((wm * 4 + i) * 64) + lane) * 8);
#pragma unroll
        for (int j = 0; j < 4; ++j)
            bfr[j] = *(const bf16x8*)(Bs + swz(((wn * 4 + j) * 64) + lane) * 8);
#pragma unroll
        for (int i = 0; i < 4; ++i)
#pragma unroll
            for (int j = 0; j < 4; ++j)
                acc[i][j] = __builtin_amdgcn_mfma_f32_16x16x32_bf16(af[i], bfr[j], acc[i][j], 0, 0, 0);
    }

    int colb = lane & 15, rowq = lane >> 4;
#pragma unroll
    for (int i = 0; i < 4; ++i)
#pragma unroll
        for (int j = 0; j < 4; ++j) {
            int col = wn * 64 + j * 16 + colb;
            float bv = bias[col];
#pragma unroll
            for (int rr = 0; rr < 4; ++rr) {
                int row = bm + wm * 64 + i * 16 + rowq * 4 + rr;
                if (row < n) {
                    float v = acc[i][j][rr] + bv;
                    C[(size_t)row * 256 + col] = (bf16)(v > 0.0f ? v : 0.0f);
                }
            }
        }
}

// ---------------- 64x64 GEMM (layer 2) FUSED with quant2 ----------------
// C row (f32, via LDS) -> per-row absmax -> biased-u8 tq + w2v = dinv*tscale.
// tb round-trip eliminated.
__global__ __launch_bounds__(256) void k_gemm2q(const bf16* __restrict__ A,
                                                const bf16* __restrict__ Bt,
                                                const float* __restrict__ dinv,
                                                unsigned char* __restrict__ tq,
                                                float* __restrict__ w2v, int n) {
    __shared__ __align__(16) bf16 As[4 * 64 * 8];
    __shared__ __align__(16) bf16 Bs[4 * 64 * 8];
    __shared__ float tbf[64][65];   // padded: store 4-way max, load 2-way
    int tid = threadIdx.x;
    int bm = blockIdx.x * 64;
    int w = tid >> 6, lane = tid & 63;
    int wm = w >> 1, wn = w & 1;

    int r = tid >> 2;
    int cq = tid & 3;
    int lds_slot = swz(((r >> 4) * 64) + cq * 16 + (r & 15));
    int arow = bm + r; if (arow > n - 1) arow = n - 1;

    f32x4 acc[2][2] = {};

    for (int k0 = 0; k0 < 256; k0 += 32) {
        __syncthreads();
        uint4 av = *(const uint4*)(A + (size_t)arow * 256 + k0 + cq * 8);
        uint4 bv = *(const uint4*)(Bt + (size_t)r * 256 + k0 + cq * 8);
        *(uint4*)(As + lds_slot * 8) = av;
        *(uint4*)(Bs + lds_slot * 8) = bv;
        __syncthreads();
#pragma unroll
        for (int i = 0; i < 2; ++i) {
            bf16x8 af = *(const bf16x8*)(As + swz((wm * 2 + i) * 64 + lane) * 8);
#pragma unroll
            for (int j = 0; j < 2; ++j) {
                bf16x8 bfr = *(const bf16x8*)(Bs + swz((wn * 2 + j) * 64 + lane) * 8);
                acc[i][j] = __builtin_amdgcn_mfma_f32_16x16x32_bf16(af, bfr, acc[i][j], 0, 0, 0);
            }
        }
    }

    // stage f32 tile in LDS
    int colb = lane & 15, rowq = lane >> 4;
    __syncthreads();
#pragma unroll
    for (int i = 0; i < 2; ++i)
#pragma unroll
        for (int j = 0; j < 2; ++j)
#pragma unroll
            for (int rr = 0; rr < 4; ++rr)
                tbf[wm * 32 + i * 16 + rowq * 4 + rr][wn * 32 + j * 16 + colb] = acc[i][j][rr];
    __syncthreads();

    // quantize: 4 threads/row, 16 cols each
    int row = tid >> 2, l4 = tid & 3;
    int grow = bm + row;
    if (grow < n) {
        float f[16], m = 0.0f;
#pragma unroll
        for (int k = 0; k < 16; ++k) { f[k] = tbf[row][l4 * 16 + k]; m = fmaxf(m, fabsf(f[k])); }
        m = fmaxf(m, __shfl_xor(m, 1));
        m = fmaxf(m, __shfl_xor(m, 2));   // 4-lane group shares a row (uniform guard)
        m = fmaxf(m, 1e-20f);
        float inv = 127.0f / m;
        int wd[4];
#pragma unroll
        for (int g = 0; g < 4; ++g) {
            int acc_w = 0;
#pragma unroll
            for (int b = 0; b < 4; ++b)
                acc_w |= ((__float2int_rn(f[g * 4 + b] * inv) + 128) & 255) << (8 * b);
            wd[g] = acc_w;
        }
        ((int4*)tq)[(size_t)grow * 4 + l4] = make_int4(wd[0], wd[1], wd[2], wd[3]);
        if (l4 == 0) w2v[grow] = dinv[grow] * (m / 127.0f);
    }
}

// ---------------- agg2 + bias + log_softmax. 8 nodes/wave, 8 lanes/node ----------------
// per-edge weight = w2v[src] = dinv[src]*tscale[src]; 8-deep rotated prefetch.
__global__ __launch_bounds__(256) void k_agg2(const unsigned char* __restrict__ tq,
                                              const float* __restrict__ w2v,
                                              const int* __restrict__ off,
                                              const int2* __restrict__ pair,
                                              const float* __restrict__ dinv,
                                              const float* __restrict__ b2,
                                              float* __restrict__ out, int n) {
    int wv = blockIdx.x * 4 + (threadIdx.x >> 6);
    int lane = threadIdx.x & 63;
    int node = wv * 8 + (lane >> 3);
    int l8 = lane & 7;
    if (node >= n) return;
    int s0 = off[node], s1 = off[node + 1];
    float dv = dinv[node];
    const unsigned char* tqb = tq + l8 * 8;  // per-lane base; gather = tqb + (p.x>>2)
    int2 ts = *(const int2*)(tqb + (size_t)node * 64);
    f32x2 a[4] = {};
    float wsum = 0.0f;
    acc8(a, ts, w2v[node], wsum);  // self loop
    int e = s0;
    if (s1 - s0 >= 8) {
        int2 p[8]; float sc[8];
#pragma unroll
        for (int q = 0; q < 8; ++q) p[q] = pair[s0 + q];
#pragma unroll
        for (int q = 0; q < 8; ++q) sc[q] = w2v[(unsigned)p[q].x >> 8];
        e = s0 + 8;
        for (; e + 8 <= s1; e += 8) {
            int2 t[8];
#pragma unroll
            for (int q = 0; q < 8; ++q) t[q] = *(const int2*)(tqb + ((unsigned)p[q].x >> 2));
            int2 pn[8];
#pragma unroll
            for (int q = 0; q < 8; ++q) pn[q] = pair[e + q];
            float scn[8];
#pragma unroll
            for (int q = 0; q < 8; ++q) scn[q] = w2v[(unsigned)pn[q].x >> 8];
#pragma unroll
            for (int q = 0; q < 8; ++q) acc8(a, t[q], sc[q], wsum);
#pragma unroll
            for (int q = 0; q < 8; ++q) { p[q] = pn[q]; sc[q] = scn[q]; }
        }
        int2 t[8];
#pragma unroll
        for (int q = 0; q < 8; ++q) t[q] = *(const int2*)(tqb + ((unsigned)p[q].x >> 2));
#pragma unroll
        for (int q = 0; q < 8; ++q) acc8(a, t[q], sc[q], wsum);
    }
    for (; e < s1; ++e) {
        int2 p = pair[e];
        float w = w2v[(unsigned)p.x >> 8];
        int2 t = *(const int2*)(tqb + ((unsigned)p.x >> 2));
        acc8(a, t, w, wsum);
    }
    float c = 128.0f * wsum;  // undo the +128 bias
    float aa[8];
#pragma unroll
    for (int j = 0; j < 4; ++j) { aa[2 * j] = a[j][0]; aa[2 * j + 1] = a[j][1]; }
    const float4* B2 = (const float4*)b2;
    float4 bv0 = B2[l8 * 2], bv1 = B2[l8 * 2 + 1];
    aa[0] = (aa[0] - c) * dv + bv0.x; aa[1] = (aa[1] - c) * dv + bv0.y;
    aa[2] = (aa[2] - c) * dv + bv0.z; aa[3] = (aa[3] - c) * dv + bv0.w;
    aa[4] = (aa[4] - c) * dv + bv1.x; aa[5] = (aa[5] - c) * dv + bv1.y;
    aa[6] = (aa[6] - c) * dv + bv1.z; aa[7] = (aa[7] - c) * dv + bv1.w;
    float m = aa[0];
#pragma unroll
    for (int j = 1; j < 8; ++j) m = fmaxf(m, aa[j]);
    for (int o = 4; o > 0; o >>= 1) m = fmaxf(m, __shfl_xor(m, o));
    float s = 0.0f;
#pragma unroll
    for (int j = 0; j < 8; ++j) s += __expf(aa[j] - m);
    for (int o = 4; o > 0; o >>= 1) s += __shfl_xor(s, o);
    float ls = m + __logf(s);
    f32x4 o0, o1;
    o0[0] = aa[0] - ls; o0[1] = aa[1] - ls; o0[2] = aa[2] - ls; o0[3] = aa[3] - ls;
    o1[0] = aa[4] - ls; o1[1] = aa[5] - ls; o1[2] = aa[6] - ls; o1[3] = aa[7] - ls;
    f32x4* O = (f32x4*)out;  // row = 16 x f32x4
    O[(size_t)node * 16 + l8 * 2] = o0;
    O[(size_t)node * 16 + l8 * 2 + 1] = o1;
}

extern "C" void kernel_launch(void* const* d_in, const int* in_sizes, int n_in,
                              void* d_out, int out_size, void* d_ws, size_t ws_size,
                              hipStream_t stream) {
    const float* x   = (const float*)d_in[0];
    const int*  edge = (const int*)d_in[1];
    const float* W1  = (const float*)d_in[2];
    const float* b1  = (const float*)d_in[3];
    const float* W2  = (const float*)d_in[4];
    const float* b2  = (const float*)d_in[5];
    float* out = (float*)d_out;

    int n = in_sizes[0] / 256;   // 100000
    int E = in_sizes[1] / 2;     // 3200000
    int NB = (n + 511) >> 9;     // node buckets (512 each); requires n < 131072
    int chunk = (E + NBLK - 1) / NBLK;

    char* ws = (char*)d_ws;
    auto alloc = [&](size_t bytes) -> char* {
        char* p = ws;
        ws += (bytes + 255) & ~(size_t)255;
        return p;
    };
    int*   gcnt   = (int*)alloc((size_t)NBLK * NB * 4);
    int*   bstart = (int*)alloc((size_t)(NB + 1) * 4);
    int*   ebuf   = (int*)alloc((size_t)E * 4);
    float* dinv   = (float*)alloc((size_t)n * 4);
    float* wsv    = (float*)alloc((size_t)n * 4);
    int*   off    = (int*)alloc((size_t)(n + 1) * 4);
    int2*  pair   = (int2*)alloc((size_t)E * 8);
    unsigned char* xqA = (unsigned char*)alloc((size_t)n * 128);
    unsigned char* xqB = (unsigned char*)alloc((size_t)n * 128);
    float* scale  = (float*)alloc((size_t)n * 4);
    bf16*  ax     = (bf16*)alloc((size_t)n * 256 * 2);
    bf16*  h1     = (bf16*)alloc((size_t)n * 256 * 2);
    unsigned char* tq = (unsigned char*)alloc((size_t)n * 64);
    float* w2v    = (float*)alloc((size_t)n * 4);
    bf16*  W1t    = (bf16*)alloc(256 * 256 * 2);
    bf16*  W2t    = (bf16*)alloc(64 * 256 * 2);

    // --- feature quant first (k_b45 folds scale into ws = dinv*scale) ---
    k_quant<<<(n + 3) / 4, 256, 0, stream>>>(x, xqA, xqB, scale, n);

    // --- CSR build (no global atomics) ---
    k_b1<<<NBLK, 256, 0, stream>>>(edge, E, chunk, NB, gcnt);
    k_b2<<<1, 256, 0, stream>>>(gcnt, NB, E, bstart);
    k_b2b<<<NB, 256, 0, stream>>>(gcnt, NB, bstart);
    k_b3<<<NBLK, 256, 0, stream>>>(edge, E, chunk, NB, gcnt, ebuf);
    k_b45<<<NB, 256, 0, stream>>>(ebuf, bstart, scale, n, E, NB, off, dinv, wsv);
    k_b6<<<NB, 256, 0, stream>>>(ebuf, bstart, off, wsv, n, pair);

    // --- weights (single launch) ---
    k_wt<<<320, 256, 0, stream>>>(W1, W2, W1t, W2t);

    // --- layer 1: two half-table aggregation passes, then GEMM ---
    k_agg1h<<<(n + 31) / 32, 256, 0, stream>>>(xqA, wsv, off, pair, dinv, ax, 0, n);
    k_agg1h<<<(n + 31) / 32, 256, 0, stream>>>(xqB, wsv, off, pair, dinv, ax, 16, n);
    k_gemmp<<<(n + 127) / 128, 512, 0, stream>>>(ax, W1t, b1, h1, n);

    // --- layer 2: GEMM fused with quantization, then aggregation ---
    k_gemm2q<<<(n + 63) / 64, 256, 0, stream>>>(h1, W2t, dinv, tq, w2v, n);
    k_agg2<<<(n + 31) / 32, 256, 0, stream>>>(tq, w2v, off, pair, dinv, b2, out, n);
}

// Round 10
// 515.032 us; speedup vs baseline: 1.0216x; 1.0216x over previous
//
#include <hip/hip_runtime.h>
#include <hip/hip_bf16.h>

// BasicGCN: out = log_softmax( A @ (relu(A @ x @ W1 + b1) @ W2) + b2 )
// R18: post-mortem-driven cleanup of R17:
//  - REVERT agg1 column-split (R17: 2x63us @3.28TB/s vs single 116.5us
//    @3.74TB/s -- per-edge overhead amortizes worse over half the bytes).
//    Back to R16's k_agg1: 4 nodes/wave, 16 lanes/node, 16B/lane, 8-deep.
//  - KEEP gemm2q (quant2 fused into gemm2 epilogue; tb round-trip gone).
//  - NEW: fuse the three input-only prep kernels (quant / b1 / wt) into one
//    k_prep launch (blockIdx-range dispatch) -- two fewer launches, and the
//    b1 histogram blocks co-schedule with quant's streaming blocks.
// b45+b6 merge was considered and rejected: b6 gathers ws[sv] cross-bucket,
// requiring all of b45 complete first.

typedef __bf16 bf16;
typedef bf16 bf16x8 __attribute__((ext_vector_type(8)));
typedef float f32x4 __attribute__((ext_vector_type(4)));
typedef float f32x2 __attribute__((ext_vector_type(2)));

#define NBLK 256  // edge-chunk blocks for bucketing passes

// ---------------- fused prep: quant (blocks 0..nqb-1) | b1 hist (next NBLK) | wt (last 320) ----
__global__ __launch_bounds__(256) void k_prep(const float* __restrict__ x,
                                              unsigned char* __restrict__ xq,
                                              float* __restrict__ scale, int n, int nqb,
                                              const int* __restrict__ edge, int E, int chunk,
                                              int NB, int* __restrict__ gcnt,
                                              const float* __restrict__ W1,
                                              const float* __restrict__ W2,
                                              bf16* __restrict__ W1t,
                                              bf16* __restrict__ W2t) {
    int b = blockIdx.x;
    int tid = threadIdx.x;
    if (b < nqb) {
        // x -> per-row-scaled biased-u8 (one wave per row); byte = rn(x*127/max)+128
        int row = b * 4 + (tid >> 6);
        int lane = tid & 63;
        if (row >= n) return;
        f32x4 v = ((const f32x4*)x)[(size_t)row * 64 + lane];
        float m = fmaxf(fmaxf(fabsf(v[0]), fabsf(v[1])), fmaxf(fabsf(v[2]), fabsf(v[3])));
        for (int o = 32; o > 0; o >>= 1) m = fmaxf(m, __shfl_xor(m, o));
        m = fmaxf(m, 1e-20f);
        float inv = 127.0f / m;
        int b0 = (__float2int_rn(v[0] * inv) + 128) & 255;
        int b1v = (__float2int_rn(v[1] * inv) + 128) & 255;
        int b2v = (__float2int_rn(v[2] * inv) + 128) & 255;
        int b3v = (__float2int_rn(v[3] * inv) + 128) & 255;
        ((int*)xq)[(size_t)row * 64 + lane] = b0 | (b1v << 8) | (b2v << 16) | (b3v << 24);
        if (lane == 0) scale[row] = m / 127.0f;
    } else if (b < nqb + NBLK) {
        // per-block bucket histogram (LDS)
        int blk = b - nqb;
        __shared__ int cnt[512];
        for (int i = tid; i < NB; i += 256) cnt[i] = 0;
        __syncthreads();
        int s = blk * chunk, e = min(s + chunk, E);
        for (int i = s + tid; i < e; i += 256) atomicAdd(&cnt[edge[E + i] >> 9], 1);
        __syncthreads();
        for (int i = tid; i < NB; i += 256) gcnt[blk * NB + i] = cnt[i];
    } else {
        // weight transposes
        int bb = b - nqb - NBLK;
        if (bb < 256) W1t[bb * 256 + tid] = (bf16)W1[tid * 256 + bb];
        else { int nc = bb - 256; W2t[nc * 256 + tid] = (bf16)W2[tid * 64 + nc]; }
    }
}

// ---------------- pass 2a: bucket starts ----------------
__global__ void k_b2(const int* __restrict__ gcnt, int NB, int E, int* __restrict__ bstart) {
    __shared__ int col[256];
    int k = threadIdx.x;
    int sum = 0;
    if (k < NB)
        for (int b = 0; b < NBLK; ++b) sum += gcnt[b * NB + k];
    col[k] = sum;
    __syncthreads();
    for (int o = 1; o < 256; o <<= 1) {
        int v = (k >= o) ? col[k - o] : 0;
        __syncthreads();
        col[k] += v;
        __syncthreads();
    }
    if (k < NB) bstart[k] = col[k] - sum;
    if (k == 0) bstart[NB] = E;
}

// ---------------- pass 2b: per-(block,bucket) bases ----------------
__global__ void k_b2b(int* __restrict__ gcnt, int NB, const int* __restrict__ bstart) {
    __shared__ int col[256];
    int b = threadIdx.x;  // NBLK == 256
    int k = blockIdx.x;
    int v = gcnt[b * NB + k];
    col[b] = v;
    __syncthreads();
    for (int o = 1; o < 256; o <<= 1) {
        int t = (b >= o) ? col[b - o] : 0;
        __syncthreads();
        col[b] += t;
        __syncthreads();
    }
    gcnt[b * NB + k] = bstart[k] + col[b] - v;
}

// ---------------- pass 3: scatter edges into bucket-grouped ebuf ----------------
// packed: src (17 bits) | (dst & 511) << 17
__global__ __launch_bounds__(256) void k_b3(const int* __restrict__ edge, int E, int chunk,
                                            int NB, const int* __restrict__ base,
                                            int* __restrict__ ebuf) {
    __shared__ int cnt[512];
    __shared__ int bs[512];
    int tid = threadIdx.x;
    for (int i = tid; i < NB; i += 256) {
        cnt[i] = 0;
        bs[i] = base[blockIdx.x * NB + i];
    }
    __syncthreads();
    int s = blockIdx.x * chunk, e = min(s + chunk, E);
    for (int i = s + tid; i < e; i += 256) {
        int sv = edge[i], dv = edge[E + i];
        int k = dv >> 9;
        int r = atomicAdd(&cnt[k], 1);  // LDS atomic
        ebuf[bs[k] + r] = sv | ((dv & 511) << 17);
    }
}

// ---------------- pass 4+5 merged: per-bucket hist + local scan -> off, dinv, ws ----------------
// off[node] = bstart[bucket] + exclusive_scan_within_bucket(deg); ws = dinv*scale
__global__ __launch_bounds__(256) void k_b45(const int* __restrict__ ebuf,
                                             const int* __restrict__ bstart,
                                             const float* __restrict__ scale, int n, int E,
                                             int NB, int* __restrict__ off,
                                             float* __restrict__ dinv,
                                             float* __restrict__ ws) {
    __shared__ int cnt[512];
    __shared__ int red[256];
    int tid = threadIdx.x;
    int k = blockIdx.x;
    cnt[tid] = 0;
    cnt[tid + 256] = 0;
    __syncthreads();
    int s = bstart[k], e = bstart[k + 1];
    for (int i = s + tid; i < e; i += 256) atomicAdd(&cnt[(ebuf[i] >> 17) & 511], 1);
    __syncthreads();
    int c0 = cnt[tid * 2], c1 = cnt[tid * 2 + 1];
    int sum = c0 + c1;
    red[tid] = sum;
    __syncthreads();
    for (int o = 1; o < 256; o <<= 1) {
        int v = (tid >= o) ? red[tid - o] : 0;
        __syncthreads();
        red[tid] += v;
        __syncthreads();
    }
    int ex = red[tid] - sum;  // exclusive prefix over pairs
    int base = k << 9;
    int g0 = base + tid * 2, g1 = g0 + 1;
    int o0 = s + ex, o1 = s + ex + c0;
    if (g0 < n) {
        off[g0] = o0;
        float d0 = rsqrtf((float)(c0 + 1));
        dinv[g0] = d0;
        ws[g0] = d0 * scale[g0];
    } else if (g0 == n) off[g0] = o0;
    if (g1 < n) {
        off[g1] = o1;
        float d1 = rsqrtf((float)(c1 + 1));
        dinv[g1] = d1;
        ws[g1] = d1 * scale[g1];
    } else if (g1 == n) off[g1] = o1;
    if (k == NB - 1 && tid == 0) off[n] = E;
}

// ---------------- pass 6: per-bucket CSR fill (LDS ranks, LDS off) ----------------
// pair.x = sv<<8 (byte offset into xq); pair.y = ws[sv] = dinv[sv]*scale[sv]
__global__ __launch_bounds__(256) void k_b6(const int* __restrict__ ebuf,
                                            const int* __restrict__ bstart,
                                            const int* __restrict__ off,
                                            const float* __restrict__ ws, int n,
                                            int2* __restrict__ pair) {
    __shared__ int cnt[512];
    __shared__ int offl[512];
    int tid = threadIdx.x;
    int k = blockIdx.x;
    int base = k << 9;
    cnt[tid] = 0;
    cnt[tid + 256] = 0;
    offl[tid] = (base + tid < n) ? off[base + tid] : 0;
    offl[tid + 256] = (base + 256 + tid < n) ? off[base + 256 + tid] : 0;
    __syncthreads();
    int s = bstart[k], e = bstart[k + 1];
    for (int i = s + tid; i < e; i += 256) {
        int pk = ebuf[i];
        int sv = pk & 0x1ffff;
        int node = (pk >> 17) & 511;
        int r = atomicAdd(&cnt[node], 1);  // LDS atomic
        pair[offl[node] + r] = make_int2(sv << 8, __float_as_int(ws[sv]));
    }
}

// accumulate 16 biased-u8 elements into 8 f32x2; wsum += w
// (float)((u>>8)&255) etc. lower to single v_cvt_f32_ubyte{0..3}
__device__ __forceinline__ void acc16(f32x2 a[8], uint4 t, float w, float& wsum) {
    wsum += w;
    f32x2 w2 = {w, w};
    unsigned u0 = t.x, u1 = t.y, u2 = t.z, u3 = t.w;
    f32x2 c;
    c[0] = (float)(u0 & 255u);         c[1] = (float)((u0 >> 8) & 255u);  a[0] += w2 * c;
    c[0] = (float)((u0 >> 16) & 255u); c[1] = (float)(u0 >> 24);         a[1] += w2 * c;
    c[0] = (float)(u1 & 255u);         c[1] = (float)((u1 >> 8) & 255u);  a[2] += w2 * c;
    c[0] = (float)((u1 >> 16) & 255u); c[1] = (float)(u1 >> 24);         a[3] += w2 * c;
    c[0] = (float)(u2 & 255u);         c[1] = (float)((u2 >> 8) & 255u);  a[4] += w2 * c;
    c[0] = (float)((u2 >> 16) & 255u); c[1] = (float)(u2 >> 24);         a[5] += w2 * c;
    c[0] = (float)(u3 & 255u);         c[1] = (float)((u3 >> 8) & 255u);  a[6] += w2 * c;
    c[0] = (float)((u3 >> 16) & 255u); c[1] = (float)(u3 >> 24);         a[7] += w2 * c;
}

// accumulate 8 biased-u8 elements into 4 f32x2
__device__ __forceinline__ void acc8(f32x2 a[4], int2 t, float w, float& wsum) {
    wsum += w;
    f32x2 w2 = {w, w};
    unsigned u0 = (unsigned)t.x, u1 = (unsigned)t.y;
    f32x2 c;
    c[0] = (float)(u0 & 255u);         c[1] = (float)((u0 >> 8) & 255u);  a[0] += w2 * c;
    c[0] = (float)((u0 >> 16) & 255u); c[1] = (float)(u0 >> 24);         a[1] += w2 * c;
    c[0] = (float)(u1 & 255u);         c[1] = (float)((u1 >> 8) & 255u);  a[2] += w2 * c;
    c[0] = (float)((u1 >> 16) & 255u); c[1] = (float)(u1 >> 24);         a[3] += w2 * c;
}

// ---------------- agg1: ax = A @ x. 4 nodes/wave, 16 lanes/node, 16B/lane ----------------
// 8-deep rotation: 8 pair loads + 8 gathers in flight.
__global__ __launch_bounds__(256) void k_agg1(const unsigned char* __restrict__ xq,
                                              const float* __restrict__ wsv,
                                              const int* __restrict__ off,
                                              const int2* __restrict__ pair,
                                              const float* __restrict__ dinv,
                                              bf16* __restrict__ ax, int n) {
    int wv = blockIdx.x * 4 + (threadIdx.x >> 6);
    int lane = threadIdx.x & 63;
    int node = wv * 4 + (lane >> 4);
    int l16 = lane & 15;
    if (node >= n) return;
    int s0 = off[node], s1 = off[node + 1];
    float dv = dinv[node];
    const unsigned char* xqb = xq + l16 * 16;  // per-lane base; gather = xqb + p.x
    f32x2 a[8] = {};
    float wsum = 0.0f;
    uint4 xs = *(const uint4*)(xqb + (size_t)node * 256);
    acc16(a, xs, wsv[node], wsum);  // self loop, weight dinv*scale[node]
    int e = s0;
    if (s1 - s0 >= 8) {
        int2 p[8];
#pragma unroll
        for (int q = 0; q < 8; ++q) p[q] = pair[s0 + q];
        e = s0 + 8;
        for (; e + 8 <= s1; e += 8) {
            uint4 t[8];
#pragma unroll
            for (int q = 0; q < 8; ++q)
                t[q] = *(const uint4*)(xqb + (unsigned)p[q].x);
            int2 pn[8];
#pragma unroll
            for (int q = 0; q < 8; ++q) pn[q] = pair[e + q];
#pragma unroll
            for (int q = 0; q < 8; ++q) acc16(a, t[q], __int_as_float(p[q].y), wsum);
#pragma unroll
            for (int q = 0; q < 8; ++q) p[q] = pn[q];
        }
        // drain the prefetched 8
        uint4 t[8];
#pragma unroll
        for (int q = 0; q < 8; ++q)
            t[q] = *(const uint4*)(xqb + (unsigned)p[q].x);
#pragma unroll
        for (int q = 0; q < 8; ++q) acc16(a, t[q], __int_as_float(p[q].y), wsum);
    }
    for (; e < s1; ++e) {
        int2 p = pair[e];
        uint4 t = *(const uint4*)(xqb + (unsigned)p.x);
        acc16(a, t, __int_as_float(p.y), wsum);
    }
    float c = 128.0f * wsum;  // undo the +128 bias
    bf16x8 o0, o1;
#pragma unroll
    for (int j = 0; j < 4; ++j) {
        o0[2 * j]     = (bf16)((a[j][0] - c) * dv);
        o0[2 * j + 1] = (bf16)((a[j][1] - c) * dv);
        o1[2 * j]     = (bf16)((a[4 + j][0] - c) * dv);
        o1[2 * j + 1] = (bf16)((a[4 + j][1] - c) * dv);
    }
    ((bf16x8*)ax)[(size_t)node * 32 + l16 * 2] = o0;
    ((bf16x8*)ax)[(size_t)node * 32 + l16 * 2 + 1] = o1;
}

// LDS slot swizzle (slot in 16B units): spreads lane-stride-16B reads across banks.
__device__ __forceinline__ int swz(int s) { return s ^ ((s >> 3) & 7); }

// ---------------- row-panel GEMM (layer 1): C[n x 256] = A[n x 256] @ Bt^T, +bias+relu ----
// 128-row panel, 8 waves (2M x 4N), acc[4][4]/wave, 8 ds_read : 16 MFMA per k-step.
__global__ __launch_bounds__(512) void k_gemmp(const bf16* __restrict__ A,
                                               const bf16* __restrict__ Bt,
                                               const float* __restrict__ bias,
                                               bf16* __restrict__ C, int n) {
    __shared__ __align__(16) bf16 As[8 * 64 * 8];    // 128 rows x 32 k (8KB)
    __shared__ __align__(16) bf16 Bs[16 * 64 * 8];   // 256 N x 32 k (16KB)
    int tid = threadIdx.x;           // 0..511
    int bm = blockIdx.x * 128;
    int w = tid >> 6, lane = tid & 63;
    int wm = w >> 2;                 // 0..1: row half (64 rows)
    int wn = w & 3;                  // 0..3: col quarter (64 cols)

    int r = tid >> 2;                // 0..127
    int cq = tid & 3;
    int a_slot = swz(((r >> 4) * 64) + cq * 16 + (r & 15));
    int arow = bm + r; if (arow > n - 1) arow = n - 1;

    f32x4 acc[4][4] = {};

    for (int k0 = 0; k0 < 256; k0 += 32) {
        __syncthreads();
        uint4 av = *(const uint4*)(A + (size_t)arow * 256 + k0 + cq * 8);
        *(uint4*)(As + a_slot * 8) = av;
#pragma unroll
        for (int rep = 0; rep < 2; ++rep) {
            int r2 = rep * 128 + r;
            uint4 bv = *(const uint4*)(Bt + (size_t)r2 * 256 + k0 + cq * 8);
            *(uint4*)(Bs + swz(((r2 >> 4) * 64) + cq * 16 + (r2 & 15)) * 8) = bv;
        }
        __syncthreads();
        bf16x8 af[4], bfr[4];
#pragma unroll
        for (int i = 0; i < 4; ++i)
            af[i] = *(const bf16x8*)(As + swz(((wm * 4 + i) * 64) + lane) * 8);
#pragma unroll
        for (int j = 0; j < 4; ++j)
            bfr[j] = *(const bf16x8*)(Bs + swz(((wn * 4 + j) * 64) + lane) * 8);
#pragma unroll
        for (int i = 0; i < 4; ++i)
#pragma unroll
            for (int j = 0; j < 4; ++j)
                acc[i][j] = __builtin_amdgcn_mfma_f32_16x16x32_bf16(af[i], bfr[j], acc[i][j], 0, 0, 0);
    }

    int colb = lane & 15, rowq = lane >> 4;
#pragma unroll
    for (int i = 0; i < 4; ++i)
#pragma unroll
        for (int j = 0; j < 4; ++j) {
            int col = wn * 64 + j * 16 + colb;
            float bv = bias[col];
#pragma unroll
            for (int rr = 0; rr < 4; ++rr) {
                int row = bm + wm * 64 + i * 16 + rowq * 4 + rr;
                if (row < n) {
                    float v = acc[i][j][rr] + bv;
                    C[(size_t)row * 256 + col] = (bf16)(v > 0.0f ? v : 0.0f);
                }
            }
        }
}

// ---------------- 64x64 GEMM (layer 2) FUSED with quant2 ----------------
// C row (f32, via LDS) -> per-row absmax -> biased-u8 tq + w2v = dinv*tscale.
__global__ __launch_bounds__(256) void k_gemm2q(const bf16* __restrict__ A,
                                                const bf16* __restrict__ Bt,
                                                const float* __restrict__ dinv,
                                                unsigned char* __restrict__ tq,
                                                float* __restrict__ w2v, int n) {
    __shared__ __align__(16) bf16 As[4 * 64 * 8];
    __shared__ __align__(16) bf16 Bs[4 * 64 * 8];
    __shared__ float tbf[64][65];
    int tid = threadIdx.x;
    int bm = blockIdx.x * 64;
    int w = tid >> 6, lane = tid & 63;
    int wm = w >> 1, wn = w & 1;

    int r = tid >> 2;
    int cq = tid & 3;
    int lds_slot = swz(((r >> 4) * 64) + cq * 16 + (r & 15));
    int arow = bm + r; if (arow > n - 1) arow = n - 1;

    f32x4 acc[2][2] = {};

    for (int k0 = 0; k0 < 256; k0 += 32) {
        __syncthreads();
        uint4 av = *(const uint4*)(A + (size_t)arow * 256 + k0 + cq * 8);
        uint4 bv = *(const uint4*)(Bt + (size_t)r * 256 + k0 + cq * 8);
        *(uint4*)(As + lds_slot * 8) = av;
        *(uint4*)(Bs + lds_slot * 8) = bv;
        __syncthreads();
#pragma unroll
        for (int i = 0; i < 2; ++i) {
            bf16x8 af = *(const bf16x8*)(As + swz((wm * 2 + i) * 64 + lane) * 8);
#pragma unroll
            for (int j = 0; j < 2; ++j) {
                bf16x8 bfr = *(const bf16x8*)(Bs + swz((wn * 2 + j) * 64 + lane) * 8);
                acc[i][j] = __builtin_amdgcn_mfma_f32_16x16x32_bf16(af, bfr, acc[i][j], 0, 0, 0);
            }
        }
    }

    // stage f32 tile in LDS
    int colb = lane & 15, rowq = lane >> 4;
    __syncthreads();
#pragma unroll
    for (int i = 0; i < 2; ++i)
#pragma unroll
        for (int j = 0; j < 2; ++j)
#pragma unroll
            for (int rr = 0; rr < 4; ++rr)
                tbf[wm * 32 + i * 16 + rowq * 4 + rr][wn * 32 + j * 16 + colb] = acc[i][j][rr];
    __syncthreads();

    // quantize: 4 threads/row, 16 cols each
    int row = tid >> 2, l4 = tid & 3;
    int grow = bm + row;
    if (grow < n) {
        float f[16], m = 0.0f;
#pragma unroll
        for (int k = 0; k < 16; ++k) { f[k] = tbf[row][l4 * 16 + k]; m = fmaxf(m, fabsf(f[k])); }
        m = fmaxf(m, __shfl_xor(m, 1));
        m = fmaxf(m, __shfl_xor(m, 2));   // 4-lane group shares a row (uniform guard)
        m = fmaxf(m, 1e-20f);
        float inv = 127.0f / m;
        int wd[4];
#pragma unroll
        for (int g = 0; g < 4; ++g) {
            int acc_w = 0;
#pragma unroll
            for (int b = 0; b < 4; ++b)
                acc_w |= ((__float2int_rn(f[g * 4 + b] * inv) + 128) & 255) << (8 * b);
            wd[g] = acc_w;
        }
        ((int4*)tq)[(size_t)grow * 4 + l4] = make_int4(wd[0], wd[1], wd[2], wd[3]);
        if (l4 == 0) w2v[grow] = dinv[grow] * (m / 127.0f);
    }
}

// ---------------- agg2 + bias + log_softmax. 8 nodes/wave, 8 lanes/node ----------------
// per-edge weight = w2v[src] = dinv[src]*tscale[src]; 8-deep rotated prefetch.
__global__ __launch_bounds__(256) void k_agg2(const unsigned char* __restrict__ tq,
                                              const float* __restrict__ w2v,
                                              const int* __restrict__ off,
                                              const int2* __restrict__ pair,
                                              const float* __restrict__ dinv,
                                              const float* __restrict__ b2,
                                              float* __restrict__ out, int n) {
    int wv = blockIdx.x * 4 + (threadIdx.x >> 6);
    int lane = threadIdx.x & 63;
    int node = wv * 8 + (lane >> 3);
    int l8 = lane & 7;
    if (node >= n) return;
    int s0 = off[node], s1 = off[node + 1];
    float dv = dinv[node];
    const unsigned char* tqb = tq + l8 * 8;  // per-lane base; gather = tqb + (p.x>>2)
    int2 ts = *(const int2*)(tqb + (size_t)node * 64);
    f32x2 a[4] = {};
    float wsum = 0.0f;
    acc8(a, ts, w2v[node], wsum);  // self loop
    int e = s0;
    if (s1 - s0 >= 8) {
        int2 p[8]; float sc[8];
#pragma unroll
        for (int q = 0; q < 8; ++q) p[q] = pair[s0 + q];
#pragma unroll
        for (int q = 0; q < 8; ++q) sc[q] = w2v[(unsigned)p[q].x >> 8];
        e = s0 + 8;
        for (; e + 8 <= s1; e += 8) {
            int2 t[8];
#pragma unroll
            for (int q = 0; q < 8; ++q) t[q] = *(const int2*)(tqb + ((unsigned)p[q].x >> 2));
            int2 pn[8];
#pragma unroll
            for (int q = 0; q < 8; ++q) pn[q] = pair[e + q];
            float scn[8];
#pragma unroll
            for (int q = 0; q < 8; ++q) scn[q] = w2v[(unsigned)pn[q].x >> 8];
#pragma unroll
            for (int q = 0; q < 8; ++q) acc8(a, t[q], sc[q], wsum);
#pragma unroll
            for (int q = 0; q < 8; ++q) { p[q] = pn[q]; sc[q] = scn[q]; }
        }
        int2 t[8];
#pragma unroll
        for (int q = 0; q < 8; ++q) t[q] = *(const int2*)(tqb + ((unsigned)p[q].x >> 2));
#pragma unroll
        for (int q = 0; q < 8; ++q) acc8(a, t[q], sc[q], wsum);
    }
    for (; e < s1; ++e) {
        int2 p = pair[e];
        float w = w2v[(unsigned)p.x >> 8];
        int2 t = *(const int2*)(tqb + ((unsigned)p.x >> 2));
        acc8(a, t, w, wsum);
    }
    float c = 128.0f * wsum;  // undo the +128 bias
    float aa[8];
#pragma unroll
    for (int j = 0; j < 4; ++j) { aa[2 * j] = a[j][0]; aa[2 * j + 1] = a[j][1]; }
    const float4* B2 = (const float4*)b2;
    float4 bv0 = B2[l8 * 2], bv1 = B2[l8 * 2 + 1];
    aa[0] = (aa[0] - c) * dv + bv0.x; aa[1] = (aa[1] - c) * dv + bv0.y;
    aa[2] = (aa[2] - c) * dv + bv0.z; aa[3] = (aa[3] - c) * dv + bv0.w;
    aa[4] = (aa[4] - c) * dv + bv1.x; aa[5] = (aa[5] - c) * dv + bv1.y;
    aa[6] = (aa[6] - c) * dv + bv1.z; aa[7] = (aa[7] - c) * dv + bv1.w;
    float m = aa[0];
#pragma unroll
    for (int j = 1; j < 8; ++j) m = fmaxf(m, aa[j]);
    for (int o = 4; o > 0; o >>= 1) m = fmaxf(m, __shfl_xor(m, o));
    float s = 0.0f;
#pragma unroll
    for (int j = 0; j < 8; ++j) s += __expf(aa[j] - m);
    for (int o = 4; o > 0; o >>= 1) s += __shfl_xor(s, o);
    float ls = m + __logf(s);
    f32x4 o0, o1;
    o0[0] = aa[0] - ls; o0[1] = aa[1] - ls; o0[2] = aa[2] - ls; o0[3] = aa[3] - ls;
    o1[0] = aa[4] - ls; o1[1] = aa[5] - ls; o1[2] = aa[6] - ls; o1[3] = aa[7] - ls;
    f32x4* O = (f32x4*)out;  // row = 16 x f32x4
    O[(size_t)node * 16 + l8 * 2] = o0;
    O[(size_t)node * 16 + l8 * 2 + 1] = o1;
}

extern "C" void kernel_launch(void* const* d_in, const int* in_sizes, int n_in,
                              void* d_out, int out_size, void* d_ws, size_t ws_size,
                              hipStream_t stream) {
    const float* x   = (const float*)d_in[0];
    const int*  edge = (const int*)d_in[1];
    const float* W1  = (const float*)d_in[2];
    const float* b1  = (const float*)d_in[3];
    const float* W2  = (const float*)d_in[4];
    const float* b2  = (const float*)d_in[5];
    float* out = (float*)d_out;

    int n = in_sizes[0] / 256;   // 100000
    int E = in_sizes[1] / 2;     // 3200000
    int NB = (n + 511) >> 9;     // node buckets (512 each); requires n < 131072
    int chunk = (E + NBLK - 1) / NBLK;

    char* ws = (char*)d_ws;
    auto alloc = [&](size_t bytes) -> char* {
        char* p = ws;
        ws += (bytes + 255) & ~(size_t)255;
        return p;
    };
    int*   gcnt   = (int*)alloc((size_t)NBLK * NB * 4);
    int*   bstart = (int*)alloc((size_t)(NB + 1) * 4);
    int*   ebuf   = (int*)alloc((size_t)E * 4);
    float* dinv   = (float*)alloc((size_t)n * 4);
    float* wsv    = (float*)alloc((size_t)n * 4);
    int*   off    = (int*)alloc((size_t)(n + 1) * 4);
    int2*  pair   = (int2*)alloc((size_t)E * 8);
    unsigned char* xq = (unsigned char*)alloc((size_t)n * 256);
    float* scale  = (float*)alloc((size_t)n * 4);
    bf16*  ax     = (bf16*)alloc((size_t)n * 256 * 2);
    bf16*  h1     = (bf16*)alloc((size_t)n * 256 * 2);
    unsigned char* tq = (unsigned char*)alloc((size_t)n * 64);
    float* w2v    = (float*)alloc((size_t)n * 4);
    bf16*  W1t    = (bf16*)alloc(256 * 256 * 2);
    bf16*  W2t    = (bf16*)alloc(64 * 256 * 2);

    // --- fused prep: quant + b1 histogram + weight transposes (one launch) ---
    int nqb = (n + 3) / 4;
    k_prep<<<nqb + NBLK + 320, 256, 0, stream>>>(x, xq, scale, n, nqb,
                                                 edge, E, chunk, NB, gcnt,
                                                 W1, W2, W1t, W2t);

    // --- CSR build (no global atomics) ---
    k_b2<<<1, 256, 0, stream>>>(gcnt, NB, E, bstart);
    k_b2b<<<NB, 256, 0, stream>>>(gcnt, NB, bstart);
    k_b3<<<NBLK, 256, 0, stream>>>(edge, E, chunk, NB, gcnt, ebuf);
    k_b45<<<NB, 256, 0, stream>>>(ebuf, bstart, scale, n, E, NB, off, dinv, wsv);
    k_b6<<<NB, 256, 0, stream>>>(ebuf, bstart, off, wsv, n, pair);

    // --- layer 1 ---
    k_agg1<<<(n + 15) / 16, 256, 0, stream>>>(xq, wsv, off, pair, dinv, ax, n);
    k_gemmp<<<(n + 127) / 128, 512, 0, stream>>>(ax, W1t, b1, h1, n);

    // --- layer 2 ---
    k_gemm2q<<<(n + 63) / 64, 256, 0, stream>>>(h1, W2t, dinv, tq, w2v, n);
    k_agg2<<<(n + 31) / 32, 256, 0, stream>>>(tq, w2v, off, pair, dinv, b2, out, n);
}